// Round 7
// baseline (997.931 us; speedup 1.0000x reference)
//
#include <hip/hip_runtime.h>

#define S_LEN 2048
#define B_SZ 2048

// Pure-VALU DPP move (no LDS pipe).
template <int CTRL>
__device__ __forceinline__ float dppmov(float v) {
  int r = __builtin_amdgcn_update_dpp(0, __builtin_bit_cast(int, v), CTRL, 0xF,
                                      0xF, true);
  return __builtin_bit_cast(float, r);
}

// Decomposition (R7): block = 256 threads = 4 waves; wave w = LAYER w.
// Within a wave: 4 batch elements x 16 gate-lanes. G = lane&15 = j*4 + ty
// (j = hidden unit = quad, ty = gate 0=i 1=f 2=g 3=o); b = lane>>4 = batch
// slot; bidx = blockIdx*4 + b. Gate gather: quad_perm DPP; own-layer h
// distribution: row_ror DPP (hv[k] = h_{(j+s*k)&3}, wh pre-rotated).
// Inter-layer handoff: ty==0 lanes publish h_j to LDS buf[tau&1][row][b][j];
// ONE __syncthreads per tick; consumer reads buf[tau&1][row-1][b] as float4
// right after the barrier, consumed NEXT tick (layer l processes t = tau-l).
// Safety: a slot is rewritten only 2 barriers after it is read.
__global__ void __launch_bounds__(256, 2)
    lstm_kernel(const float *__restrict__ x, const float *__restrict__ Wih0,
                const float *__restrict__ Whh0, const float *__restrict__ bih0,
                const float *__restrict__ bhh0, const float *__restrict__ Wihr,
                const float *__restrict__ Whhr, const float *__restrict__ bihr,
                const float *__restrict__ bhhr, const float *__restrict__ Wout,
                const float *__restrict__ bout, float *__restrict__ out) {
  // 2 ping-pong buffers x [4 layers][4 batches][4 hidden] + 64-float trash
  __shared__ __align__(16) float slotf[192];
  float4 *slot4 = (float4 *)slotf;

  const int tid = threadIdx.x;
  const int lane = tid & 63;
  const int row = tid >> 6;            // wave index = layer (wave-uniform)
  const int b = lane >> 4;             // batch slot within wave
  const int G = lane & 15;
  const int ty = G & 3;                // gate type 0=i 1=f 2=g 3=o
  const int j = G >> 2;                // hidden unit (quad)
  const int bidx = blockIdx.x * 4 + b; // batch element
  const int wrow = ty * 4 + j;         // PyTorch weight row = type*H + j
  const int rl = (row + 3) & 3;        // previous layer (row0: dummy, x0 wt)
  const int rdq = rl * 4 + b;          // float4 slot within a buffer
  const int wbase = row * 16 + b * 4 + j;
  const int wrA = (ty == 0) ? wbase : (128 + lane);
  const int wrB = (ty == 0) ? (64 + wbase) : (128 + lane);

  if (tid < 192) slotf[tid] = 0.0f;
  __syncthreads();

  // ---- ROW_ROR direction probe (init-only, direction-proof) ----
  float pr = dppmov<0x124>((float)j);
  const int s = (((int)pr) - j) & 3;
  int rix[4] = {j, (j + s) & 3, (j + 2) & 3, (j + 3 * s) & 3};

  // per-lane activation constants: sigmoid for i,f,o; tanh for g
  const float L2E = 1.4426950408889634f;
  const float kk = (ty == 2) ? -2.0f * L2E : -L2E;
  const float mm = (ty == 2) ? 2.0f : 1.0f;
  const float dd = (ty == 2) ? -1.0f : 0.0f;
  const float KT = -2.8853900817779268f;  // -2*log2(e)

  // ---- this layer's weight rows (wave-uniform layer choice) ----
  float wx0 = 0.f, wx1 = 0.f, wiH[4] = {0, 0, 0, 0}, wh[4], bias;
  if (row == 0) {
    wx0 = kk * Wih0[wrow * 2 + 0];
    wx1 = kk * Wih0[wrow * 2 + 1];
#pragma unroll
    for (int k = 0; k < 4; ++k) wh[k] = kk * Whh0[wrow * 4 + rix[k]];
    bias = kk * (bih0[wrow] + bhh0[wrow]);
  } else {
    const int l = row - 1;
#pragma unroll
    for (int k = 0; k < 4; ++k) {
      wiH[k] = kk * Wihr[l * 64 + wrow * 4 + k];
      wh[k] = kk * Whhr[l * 64 + wrow * 4 + rix[k]];
    }
    bias = kk * (bihr[l * 16 + wrow] + bhhr[l * 16 + wrow]);
  }
  float wo[4];
#pragma unroll
  for (int k = 0; k < 4; ++k) wo[k] = Wout[rix[k]];
  const float bo = bout[0];

  // ---- recurrent state ----
  float hv[4] = {0, 0, 0, 0};  // own-layer h (rotated order)
  float4 hinA = {0, 0, 0, 0};  // prev-layer h (natural order), ping
  float4 hinB = {0, 0, 0, 0};  //                               pong
  float c = 0.0f;

  const float2 *__restrict__ px = (const float2 *)x;  // [S*B] float2 (IN=2)
  float *__restrict__ outp = out;

  // one tick: consume hc (prev layer h from last tick), publish this tick's
  // h, barrier, read hn for next tick. P = tau&1 selects ping-pong buffer.
  auto tick = [&](int P, bool st, float2 xv, int tt, float4 &hc, float4 &hn) {
    float a;
    if (row == 0) {  // wave-uniform branch
      float t0 = fmaf(wx1, xv.y, fmaf(wx0, xv.x, bias));
      float t2 = fmaf(wh[1], hv[1], wh[0] * hv[0]);
      float t3 = fmaf(wh[3], hv[3], wh[2] * hv[2]);
      a = t0 + (t2 + t3);
    } else {
      float t0 = fmaf(wiH[1], hc.y, fmaf(wiH[0], hc.x, bias));
      float t1 = fmaf(wiH[3], hc.w, wiH[2] * hc.z);
      float t2 = fmaf(wh[1], hv[1], wh[0] * hv[0]);
      float t3 = fmaf(wh[3], hv[3], wh[2] * hv[2]);
      a = (t0 + t1) + (t2 + t3);
    }
    float e = __builtin_amdgcn_exp2f(a);
    float r = __builtin_amdgcn_rcpf(1.0f + e);
    float g = fmaf(mm, r, dd);
    float q = g * dppmov<0x4E>(g);  // i*g lands on ty0 lane
    float pig = dppmov<0x00>(q);
    float gf = dppmov<0x55>(g);
    float go = dppmov<0xFF>(g);
    c = fmaf(gf, c, pig);
    float te = __builtin_amdgcn_exp2f(c * KT);
    float tr = __builtin_amdgcn_rcpf(1.0f + te);
    float hh = go * fmaf(2.0f, tr, -1.0f);
    hv[0] = hh;
    hv[1] = dppmov<0x124>(hh);
    hv[2] = dppmov<0x128>(hh);
    hv[3] = dppmov<0x12C>(hh);
    slotf[P ? wrB : wrA] = hh;  // unpredicated; non-ty0 lanes hit trash
    __syncthreads();
    hn = slot4[P * 16 + rdq];   // what was just published, for NEXT tick
    if (st && row == 3) {       // wave-uniform
      float y = fmaf(
          wo[0], hv[0],
          fmaf(wo[1], hv[1], fmaf(wo[2], hv[2], fmaf(wo[3], hv[3], bo))));
      if (G == 0) outp[tt * B_SZ + bidx] = y;
    }
  };

  // ---- warm-up ticks 0..2 (pipeline fill; zero not-yet-live layers) ----
  {
    float2 xv = {0.f, 0.f};
    if (row == 0) xv = px[0 * B_SZ + bidx];
    tick(0, false, xv, 0, hinA, hinB);
    if (row > 0) { c = 0; hv[0] = hv[1] = hv[2] = hv[3] = 0; }
    if (row == 0) xv = px[1 * B_SZ + bidx];
    tick(1, false, xv, 0, hinB, hinA);
    if (row > 1) { c = 0; hv[0] = hv[1] = hv[2] = hv[3] = 0; }
    if (row == 0) xv = px[2 * B_SZ + bidx];
    tick(0, false, xv, 0, hinA, hinB);
    if (row > 2) { c = 0; hv[0] = hv[1] = hv[2] = hv[3] = 0; }
  }

  // ---- x prefetch (wave 0 only; 8 ticks deep, per-lane own-batch load) ----
  float2 xq[8];
  if (row == 0) {
#pragma unroll
    for (int u = 0; u < 8; ++u) xq[u] = px[(3 + u) * B_SZ + bidx];
  }

  // ---- main loop: ticks 3..2050 (2048 = 256 x 8); tt = tau - 3 ----
  for (int it = 0; it < 256; ++it) {
#pragma unroll
    for (int u = 0; u < 8; ++u) {
      const int tt = it * 8 + u;
      float2 xv = {0.f, 0.f};
      if (row == 0) {  // wave-uniform
        xv = xq[u];
        int t = tt + 11;                   // = tau + 8
        if (t > S_LEN - 1) t = S_LEN - 1;  // clamp: drain never stored
        xq[u] = px[t * B_SZ + bidx];
      }
      if ((u & 1) == 0) {
        tick(1, true, xv, tt, hinB, hinA);
      } else {
        tick(0, true, xv, tt, hinA, hinB);
      }
    }
  }
}

extern "C" void kernel_launch(void *const *d_in, const int *in_sizes, int n_in,
                              void *d_out, int out_size, void *d_ws,
                              size_t ws_size, hipStream_t stream) {
  (void)in_sizes;
  (void)n_in;
  (void)out_size;
  (void)d_ws;
  (void)ws_size;
  const float *x = (const float *)d_in[0];
  const float *Wih0 = (const float *)d_in[1];
  const float *Whh0 = (const float *)d_in[2];
  const float *bih0 = (const float *)d_in[3];
  const float *bhh0 = (const float *)d_in[4];
  const float *Wihr = (const float *)d_in[5];
  const float *Whhr = (const float *)d_in[6];
  const float *bihr = (const float *)d_in[7];
  const float *bhhr = (const float *)d_in[8];
  const float *Wout = (const float *)d_in[9];
  const float *bout = (const float *)d_in[10];
  lstm_kernel<<<dim3(B_SZ / 4), dim3(256), 0, stream>>>(
      x, Wih0, Whh0, bih0, bhh0, Wihr, Whhr, bihr, bhhr, Wout, bout,
      (float *)d_out);
}

// Round 8
// 447.020 us; speedup vs baseline: 2.2324x; 2.2324x over previous
//
#include <hip/hip_runtime.h>

#define S_LEN 2048
#define B_SZ 2048

// Pure-VALU DPP move (no LDS pipe).
template <int CTRL>
__device__ __forceinline__ float dppmov(float v) {
  int r = __builtin_amdgcn_update_dpp(0, __builtin_bit_cast(int, v), CTRL, 0xF,
                                      0xF, true);
  return __builtin_bit_cast(float, r);
}

// readlane: broadcast lane L's value to an SGPR (no memory counter).
__device__ __forceinline__ float rlane(float v, int l) {
  return __builtin_bit_cast(
      float, __builtin_amdgcn_readlane(__builtin_bit_cast(int, v), l));
}

// Decomposition (R5 structure): wave = 1 batch element. Row r (16 lanes) =
// layer r. G = lane&15 = j*4 + ty (j = hidden unit = quad, ty = gate
// 0=i 1=f 2=g 3=o). Gate gather: quad_perm DPP. Own-layer h distribution:
// row_ror DPP (hv[k] = h_{(j+s*k)&3}, wh pre-rotated). Inter-layer: ty==0
// lanes publish h to LDS slot[row][j] (others hit a trash bin -> no exec
// masking); each lane reads slot[row-1] as one b128 at tick bottom, consumed
// next tick. Layer l at tick tau processes t = tau - l.
// R8 change: y is NOT stored per tick. It is computed into a per-chunk
// register buffer; stores are issued as one exec-masked 8-store burst per
// 8 ticks (kills the per-tick vmcnt drain + saveexec dance).
#define TICK(XVX, XVY, YOUT)                                                   \
  do {                                                                         \
    float i0 = is_row0 ? (XVX) : hin[0];                                       \
    float i1 = is_row0 ? (XVY) : hin[1];                                       \
    float t2 = fmaf(wh[1], hv[1], wh[0] * hv[0]);                              \
    float t3 = fmaf(wh[3], hv[3], wh[2] * hv[2]);                              \
    float t0 = fmaf(wi[1], i1, fmaf(wi[0], i0, bias));                         \
    float t1 = fmaf(wi[3], hin[3], wi[2] * hin[2]);                            \
    float a = (t0 + t1) + (t2 + t3);                                           \
    float e = __builtin_amdgcn_exp2f(a);                                       \
    float r = __builtin_amdgcn_rcpf(1.0f + e);                                 \
    float g = fmaf(mm, r, dd);                                                 \
    float q = g * dppmov<0x4E>(g); /* i*g lands on ty0 lane */                 \
    float pig = dppmov<0x00>(q);                                               \
    float gf = dppmov<0x55>(g);                                                \
    float go = dppmov<0xFF>(g);                                                \
    c = fmaf(gf, c, pig);                                                      \
    float te = __builtin_amdgcn_exp2f(c * KT);                                 \
    float tr = __builtin_amdgcn_rcpf(1.0f + te);                               \
    float hh = go * fmaf(2.0f, tr, -1.0f);                                     \
    hv[0] = hh;                                                                \
    hv[1] = dppmov<0x124>(hh);                                                 \
    hv[2] = dppmov<0x128>(hh);                                                 \
    hv[3] = dppmov<0x12C>(hh);                                                 \
    slotf[wr_off] = hh; /* unpredicated: non-ty0 lanes hit trash bin */        \
    __builtin_amdgcn_wave_barrier();                                           \
    float4 nh = slot4[rd_slot];                                                \
    hin[0] = nh.x;                                                             \
    hin[1] = nh.y;                                                             \
    hin[2] = nh.z;                                                             \
    hin[3] = nh.w;                                                             \
    YOUT = fmaf(wo[0], hv[0],                                                  \
                fmaf(wo[1], hv[1], fmaf(wo[2], hv[2], fmaf(wo[3], hv[3], bo))));\
  } while (0)

__global__ void __launch_bounds__(64, 2)
    lstm_kernel(const float *__restrict__ x, const float *__restrict__ Wih0,
                const float *__restrict__ Whh0, const float *__restrict__ bih0,
                const float *__restrict__ bhh0, const float *__restrict__ Wihr,
                const float *__restrict__ Whhr, const float *__restrict__ bihr,
                const float *__restrict__ bhhr, const float *__restrict__ Wout,
                const float *__restrict__ bout, float *__restrict__ out) {
  // 16 real slots (layer x hidden) + 64-float trash bin (one per lane)
  __shared__ __align__(16) float slotf[80];
  float4 *slot4 = (float4 *)slotf;

  const int lane = threadIdx.x & 63;
  const int ty = lane & 3;             // gate type
  const int j = (lane >> 2) & 3;       // hidden unit (quad)
  const int row = lane >> 4;           // layer
  const int bidx = blockIdx.x;         // batch element (1 per wave)
  const int wrow = ty * 4 + j;         // PyTorch weight row = type*H + j
  const bool is_row0 = (row == 0);
  const bool do_store = (lane == 48);  // layer 3, G==0
  const int wr_off = (ty == 0) ? ((row << 2) | j) : (16 + lane);
  const int rd_slot = (row + 3) & 3;   // layer row-1's slot (row0: ignored)

  // zero-init LDS so pre-real garbage stays finite
  slotf[lane] = 0.0f;
  slotf[16 + lane] = 0.0f;
  __builtin_amdgcn_wave_barrier();

  // ---- detect ROW_ROR direction (init-only, direction-proof) ----
  float pr = dppmov<0x124>((float)j);
  const int s = (((int)pr) - j) & 3;
  int rix[4] = {j, (j + s) & 3, (j + 2) & 3, (j + 3 * s) & 3};

  // per-lane activation constants: sigmoid for i,f,o; tanh for g
  const float L2E = 1.4426950408889634f;
  const float kk = (ty == 2) ? -2.0f * L2E : -L2E;
  const float mm = (ty == 2) ? 2.0f : 1.0f;
  const float dd = (ty == 2) ? -1.0f : 0.0f;
  const float KT = -2.8853900817779268f;  // -2*log2(e)

  // ---- this layer's weight row; wi natural order (hin arrives natural),
  //      wh pre-rotated; all pre-scaled by kk ----
  float wi[4], wh[4], bias;
  if (row == 0) {
    wi[0] = kk * Wih0[wrow * 2 + 0];
    wi[1] = kk * Wih0[wrow * 2 + 1];
    wi[2] = 0.0f;
    wi[3] = 0.0f;
#pragma unroll
    for (int k = 0; k < 4; ++k) wh[k] = kk * Whh0[wrow * 4 + rix[k]];
    bias = kk * (bih0[wrow] + bhh0[wrow]);
  } else {
    const int l = row - 1;
#pragma unroll
    for (int k = 0; k < 4; ++k) {
      wi[k] = kk * Wihr[l * 64 + wrow * 4 + k];
      wh[k] = kk * Whhr[l * 64 + wrow * 4 + rix[k]];
    }
    bias = kk * (bihr[l * 16 + wrow] + bhhr[l * 16 + wrow]);
  }
  float wo[4];
#pragma unroll
  for (int k = 0; k < 4; ++k) wo[k] = Wout[rix[k]];
  const float bo = bout[0];

  // ---- recurrent state ----
  float hv[4] = {0, 0, 0, 0};   // own layer h (rotated order)
  float hin[4] = {0, 0, 0, 0};  // prev layer h (natural order)
  float c = 0.0f;

  const float2 *__restrict__ px = (const float2 *)x;  // [S*B] float2 (IN=2)

  // divergent x loader: lane (lane&7) fetches tick base+(lane&7); a single
  // global_load_dwordx2 per 8 ticks, vmcnt domain (no lgkmcnt pollution).
  const int l8 = lane & 7;
  auto ldx = [&](int base) -> float2 {
    int t = base + l8;
    if (t > S_LEN - 1) t = S_LEN - 1;  // clamp: drain values never stored
    return px[t * B_SZ + bidx];
  };

  // ---- warm-up ticks 0..2 (plain loads; one-time) ----
  {
    float ydump;
    float2 xv = px[0 * B_SZ + bidx];
    TICK(xv.x, xv.y, ydump);
    if (row > 0) { c = 0; hv[0] = hv[1] = hv[2] = hv[3] = 0; }
    xv = px[1 * B_SZ + bidx];
    TICK(xv.x, xv.y, ydump);
    if (row > 1) { c = 0; hv[0] = hv[1] = hv[2] = hv[3] = 0; }
    xv = px[2 * B_SZ + bidx];
    TICK(xv.x, xv.y, ydump);
    if (row > 2) { c = 0; hv[0] = hv[1] = hv[2] = hv[3] = 0; }
    (void)ydump;
  }

  // ---- x double-buffer: 16..24 ticks ahead ----
  float2 xa = ldx(3);   // ticks 3..10   (iter u 0..7)
  float2 xb = ldx(11);  // ticks 11..18  (iter u 8..15)

  // ---- main loop: ticks 3..2050 (2048 = 128 x 16); tt = tau - 3 ----
  for (int it = 0; it < 128; ++it) {
    const int tt0 = it * 16;
    float2 xn1 = ldx(19 + it * 16);  // refill for next iter's first half
    float2 xn2 = ldx(27 + it * 16);  //                      second half
    // first 8 ticks -> ya
    float ya[8];
#pragma unroll
    for (int u = 0; u < 8; ++u) {
      float xvx = rlane(xa.x, u);
      float xvy = rlane(xa.y, u);
      TICK(xvx, xvy, ya[u]);
    }
    if (do_store) {  // one exec-mask dance, 8 stores; ya rewritten 16 ticks
#pragma unroll      // later -> no vmcnt wait on data regs
      for (int u = 0; u < 8; ++u) out[(tt0 + u) * B_SZ + bidx] = ya[u];
    }
    // second 8 ticks -> yb
    float yb[8];
#pragma unroll
    for (int u = 0; u < 8; ++u) {
      float xvx = rlane(xb.x, u);
      float xvy = rlane(xb.y, u);
      TICK(xvx, xvy, yb[u]);
    }
    if (do_store) {
#pragma unroll
      for (int u = 0; u < 8; ++u) out[(tt0 + 8 + u) * B_SZ + bidx] = yb[u];
    }
    xa = xn1;
    xb = xn2;
  }
}

extern "C" void kernel_launch(void *const *d_in, const int *in_sizes, int n_in,
                              void *d_out, int out_size, void *d_ws,
                              size_t ws_size, hipStream_t stream) {
  (void)in_sizes;
  (void)n_in;
  (void)out_size;
  (void)d_ws;
  (void)ws_size;
  const float *x = (const float *)d_in[0];
  const float *Wih0 = (const float *)d_in[1];
  const float *Whh0 = (const float *)d_in[2];
  const float *bih0 = (const float *)d_in[3];
  const float *bhh0 = (const float *)d_in[4];
  const float *Wihr = (const float *)d_in[5];
  const float *Whhr = (const float *)d_in[6];
  const float *bihr = (const float *)d_in[7];
  const float *bhhr = (const float *)d_in[8];
  const float *Wout = (const float *)d_in[9];
  const float *bout = (const float *)d_in[10];
  lstm_kernel<<<dim3(B_SZ), dim3(64), 0, stream>>>(
      x, Wih0, Whh0, bih0, bhh0, Wihr, Whhr, bihr, bhhr, Wout, bout,
      (float *)d_out);
}

// Round 9
// 384.947 us; speedup vs baseline: 2.5924x; 1.1613x over previous
//
#include <hip/hip_runtime.h>

#define S_LEN 2048
#define B_SZ 2048

// Pure-VALU DPP move (no LDS pipe).
template <int CTRL>
__device__ __forceinline__ float dppmov(float v) {
  int r = __builtin_amdgcn_update_dpp(0, __builtin_bit_cast(int, v), CTRL, 0xF,
                                      0xF, true);
  return __builtin_bit_cast(float, r);
}

// Decomposition (R5 lineage): wave = 1 batch element; 16-lane row r = layer
// r; G = lane&15 = j*4 + ty (j = hidden unit = quad, ty = gate 0=i 1=f 2=g
// 3=o). Gate gather: quad_perm DPP; own-layer h distribution: row_ror DPP
// (hv[k] = h_{(j+s*k)&3}, wh pre-rotated). Inter-layer handoff via LDS h
// slots, read as one b128 at tick bottom, consumed next tick.
// R9: (a) cell state kept as cKT = KT*c (KT folded into ty0's activation
// constant -> the tanh-input mul vanishes); (b) hh = fma(2*go, tr, -go);
// (c) x delivered through LDS x-regions so ALL rows read their input with
// the same b128 (no cndmask/readlane); (d) one-time s_sleep stagger to
// de-phase-lock the 2 waves sharing a SIMD.
//
// LDS float map: [0..15] h slots | [16..79] x region0 (16 entries x
// {x0,x1,0,0}) | [80..143] x region1 | [144..207] trash.

#define TICK(YOUT)                                                             \
  do {                                                                         \
    float t0 = fmaf(wi[1], hin.y, fmaf(wi[0], hin.x, bias));                   \
    float t1 = fmaf(wi[3], hin.w, wi[2] * hin.z);                              \
    float t2 = fmaf(wh[1], hv[1], wh[0] * hv[0]);                              \
    float t3 = fmaf(wh[3], hv[3], wh[2] * hv[2]);                              \
    float a = (t0 + t1) + (t2 + t3);                                           \
    float e = __builtin_amdgcn_exp2f(a);                                       \
    float r = __builtin_amdgcn_rcpf(1.0f + e);                                 \
    float g = fmaf(mm, r, dd); /* ty0 lane: g = KT*sigmoid (KT folded) */      \
    float q = g * dppmov<0x4E>(g); /* ty0 gets KT*i*g */                       \
    float pig = dppmov<0x00>(q);                                               \
    float gf = dppmov<0x55>(g);                                                \
    float go = dppmov<0xFF>(g);                                                \
    cKT = fmaf(gf, cKT, pig); /* = KT * c  (exactly the exp2 input) */         \
    float te = __builtin_amdgcn_exp2f(cKT);                                    \
    float tr = __builtin_amdgcn_rcpf(1.0f + te);                               \
    float go2 = go + go;                                                       \
    float hh = fmaf(go2, tr, -go); /* = go * tanh(c) */                        \
    hv[0] = hh;                                                                \
    hv[1] = dppmov<0x124>(hh);                                                 \
    hv[2] = dppmov<0x128>(hh);                                                 \
    hv[3] = dppmov<0x12C>(hh);                                                 \
    slotf[wr_off] = hh; /* unpredicated: non-ty0 lanes hit trash */            \
    __builtin_amdgcn_wave_barrier();                                           \
    hin = *(const float4 *)(slotf + rdoff); /* next tick's input (h or x) */   \
    rdoff += rstep;                                                            \
    YOUT = fmaf(wo[0], hv[0],                                                  \
                fmaf(wo[1], hv[1],                                             \
                     fmaf(wo[2], hv[2], fmaf(wo[3], hv[3], bo))));             \
  } while (0)

// warm-up tick: x injected via selects (one-time path); bottom-read from the
// fixed h-slot address for all rows.
#define WTICK(XVX, XVY)                                                        \
  do {                                                                         \
    float i0 = is_row0 ? (XVX) : hin.x;                                        \
    float i1 = is_row0 ? (XVY) : hin.y;                                        \
    float t0 = fmaf(wi[1], i1, fmaf(wi[0], i0, bias));                         \
    float t1 = fmaf(wi[3], hin.w, wi[2] * hin.z);                              \
    float t2 = fmaf(wh[1], hv[1], wh[0] * hv[0]);                              \
    float t3 = fmaf(wh[3], hv[3], wh[2] * hv[2]);                              \
    float a = (t0 + t1) + (t2 + t3);                                           \
    float e = __builtin_amdgcn_exp2f(a);                                       \
    float r = __builtin_amdgcn_rcpf(1.0f + e);                                 \
    float g = fmaf(mm, r, dd);                                                 \
    float q = g * dppmov<0x4E>(g);                                             \
    float pig = dppmov<0x00>(q);                                               \
    float gf = dppmov<0x55>(g);                                                \
    float go = dppmov<0xFF>(g);                                                \
    cKT = fmaf(gf, cKT, pig);                                                  \
    float te = __builtin_amdgcn_exp2f(cKT);                                    \
    float tr = __builtin_amdgcn_rcpf(1.0f + te);                               \
    float go2 = go + go;                                                       \
    float hh = fmaf(go2, tr, -go);                                             \
    hv[0] = hh;                                                                \
    hv[1] = dppmov<0x124>(hh);                                                 \
    hv[2] = dppmov<0x128>(hh);                                                 \
    hv[3] = dppmov<0x12C>(hh);                                                 \
    slotf[wr_off] = hh;                                                        \
    __builtin_amdgcn_wave_barrier();                                           \
    hin = *(const float4 *)(slotf + hoff);                                     \
  } while (0)

__global__ void __launch_bounds__(64, 2)
    lstm_kernel(const float *__restrict__ x, const float *__restrict__ Wih0,
                const float *__restrict__ Whh0, const float *__restrict__ bih0,
                const float *__restrict__ bhh0, const float *__restrict__ Wihr,
                const float *__restrict__ Whhr, const float *__restrict__ bihr,
                const float *__restrict__ bhhr, const float *__restrict__ Wout,
                const float *__restrict__ bout, float *__restrict__ out) {
  __shared__ __align__(16) float slotf[208];

  const int lane = threadIdx.x & 63;
  const int ty = lane & 3;             // gate type
  const int j = (lane >> 2) & 3;       // hidden unit (quad)
  const int row = lane >> 4;           // layer
  const int l16 = lane & 15;
  const int bidx = blockIdx.x;         // batch element (1 per wave)
  const int wrow = ty * 4 + j;         // PyTorch weight row = type*H + j
  const bool is_row0 = (row == 0);
  const bool do_store = (lane == 48);  // layer 3, G==0
  const int wr_off = (ty == 0) ? ((row << 2) | j) : (144 + lane);
  const int hoff = ((row + 3) & 3) * 4;           // fixed h-slot (floats)
  const int rbase = is_row0 ? 16 : hoff;          // main-loop read base
  const int rstep = is_row0 ? 4 : 0;              // advance per tick
  const int rbig = is_row0 ? 128 : 0;             // wrap per 32 ticks

  // zero-init all LDS (h slots, x pads, trash) so garbage stays finite
  slotf[lane] = 0.0f;
  slotf[64 + lane] = 0.0f;
  slotf[128 + lane] = 0.0f;
  if (lane < 16) slotf[192 + lane] = 0.0f;
  __builtin_amdgcn_wave_barrier();

  // ---- ROW_ROR direction probe (init-only, direction-proof) ----
  float pr = dppmov<0x124>((float)j);
  const int s = (((int)pr) - j) & 3;
  int rix[4] = {j, (j + s) & 3, (j + 2) & 3, (j + 3 * s) & 3};

  // activation constants; KT folded into ty0 (i-gate) so cKT = KT*c directly
  const float L2E = 1.4426950408889634f;
  const float KT = -2.8853900817779268f;  // -2*log2(e)
  const float kk = (ty == 2) ? -2.0f * L2E : -L2E;
  const float mm = (ty == 2) ? 2.0f : ((ty == 0) ? KT : 1.0f);
  const float dd = (ty == 2) ? -1.0f : 0.0f;

  // ---- weight rows: wi natural (hin natural), wh pre-rotated, kk-scaled ----
  float wi[4], wh[4], bias;
  if (row == 0) {
    wi[0] = kk * Wih0[wrow * 2 + 0];
    wi[1] = kk * Wih0[wrow * 2 + 1];
    wi[2] = 0.0f;
    wi[3] = 0.0f;
#pragma unroll
    for (int k = 0; k < 4; ++k) wh[k] = kk * Whh0[wrow * 4 + rix[k]];
    bias = kk * (bih0[wrow] + bhh0[wrow]);
  } else {
    const int l = row - 1;
#pragma unroll
    for (int k = 0; k < 4; ++k) {
      wi[k] = kk * Wihr[l * 64 + wrow * 4 + k];
      wh[k] = kk * Whhr[l * 64 + wrow * 4 + rix[k]];
    }
    bias = kk * (bihr[l * 16 + wrow] + bhhr[l * 16 + wrow]);
  }
  float wo[4];
#pragma unroll
  for (int k = 0; k < 4; ++k) wo[k] = Wout[rix[k]];
  const float bo = bout[0];

  // ---- recurrent state ----
  float hv[4] = {0, 0, 0, 0};      // own-layer h (rotated order)
  float4 hin = {0, 0, 0, 0};       // input: prev-layer h, or x for row 0
  float cKT = 0.0f;                // KT * cell state

  const float2 *__restrict__ px = (const float2 *)x;  // [S*B] float2 (IN=2)

  // lane l16 loads x for tick base+l16 (clamped; drains never stored)
  auto ldx16 = [&](int base) -> float2 {
    int t = base + l16;
    if (t > S_LEN - 1) t = S_LEN - 1;
    return px[t * B_SZ + bidx];
  };

  // ---- warm-up ticks 0..2 (select path; one-time) ----
  {
    float2 xv = px[0 * B_SZ + bidx];
    WTICK(xv.x, xv.y);
    if (row > 0) { cKT = 0; hv[0] = hv[1] = hv[2] = hv[3] = 0; }
    xv = px[1 * B_SZ + bidx];
    WTICK(xv.x, xv.y);
    if (row > 1) { cKT = 0; hv[0] = hv[1] = hv[2] = hv[3] = 0; }
    xv = px[2 * B_SZ + bidx];
    WTICK(xv.x, xv.y);
    if (row > 2) { cKT = 0; hv[0] = hv[1] = hv[2] = hv[3] = 0; }
  }

  // ---- prime x staging: region0 = x[3..18], region1 = x[19..34] ----
  {
    float2 w0 = ldx16(3);
    float2 w1 = ldx16(19);
    *(float2 *)(slotf + 16 + 4 * l16) = w0;  // same-addr collisions benign
    *(float2 *)(slotf + 80 + 4 * l16) = w1;
    __builtin_amdgcn_wave_barrier();
  }
  float2 gxa = ldx16(35);  // for region0 rewrite at u==15 of iter 0
  float2 gxb = ldx16(51);  // for region1 rewrite at u==31 of iter 0

  int rdoff = rbase;
  // pre-read: row0 gets x[3]; rows 1-3 refresh their h slot (idempotent)
  hin = *(const float4 *)(slotf + rdoff);
  rdoff += rstep;

  // ---- de-phase co-resident waves (one-time, deterministic) ----
  if (blockIdx.x & 1024) __builtin_amdgcn_s_sleep(4);
  if (blockIdx.x & 256) __builtin_amdgcn_s_sleep(2);
  if (blockIdx.x & 4) __builtin_amdgcn_s_sleep(1);

  // ---- main loop: 64 iters x 32 ticks; tick tau = 3 + 32*k + u ----
  float ya[8];
  for (int k = 0; k < 64; ++k) {
    const int tb = k * 32;  // tt (= tau-3) of u==0
#pragma unroll
    for (int u = 0; u < 32; ++u) {
      if (u == 15) {  // region0 reads done (last at u==14); rewrite for next
        *(float2 *)(slotf + 16 + 4 * l16) = gxa;
        gxa = ldx16(67 + 32 * k);
      }
      if (u == 31) {  // region1 reads done (last at u==30); rewrite for next
        *(float2 *)(slotf + 80 + 4 * l16) = gxb;
        gxb = ldx16(83 + 32 * k);
        rdoff -= rbig;  // row0 wraps to region0 entry 0 (x[35+32k])
      }
      TICK(ya[u & 7]);
      if ((u & 7) == 7 && do_store) {  // 8-store burst, amortized exec dance
#pragma unroll
        for (int v = 0; v < 8; ++v)
          out[(tb + (u & 24) + v) * B_SZ + bidx] = ya[v];
      }
    }
  }
}

extern "C" void kernel_launch(void *const *d_in, const int *in_sizes, int n_in,
                              void *d_out, int out_size, void *d_ws,
                              size_t ws_size, hipStream_t stream) {
  (void)in_sizes;
  (void)n_in;
  (void)out_size;
  (void)d_ws;
  (void)ws_size;
  const float *x = (const float *)d_in[0];
  const float *Wih0 = (const float *)d_in[1];
  const float *Whh0 = (const float *)d_in[2];
  const float *bih0 = (const float *)d_in[3];
  const float *bhh0 = (const float *)d_in[4];
  const float *Wihr = (const float *)d_in[5];
  const float *Whhr = (const float *)d_in[6];
  const float *bihr = (const float *)d_in[7];
  const float *bhhr = (const float *)d_in[8];
  const float *Wout = (const float *)d_in[9];
  const float *bout = (const float *)d_in[10];
  lstm_kernel<<<dim3(B_SZ), dim3(64), 0, stream>>>(
      x, Wih0, Whh0, bih0, bhh0, Wihr, Whhr, bihr, bhhr, Wout, bout,
      (float *)d_out);
}

// Round 10
// 381.820 us; speedup vs baseline: 2.6136x; 1.0082x over previous
//
#include <hip/hip_runtime.h>

#define S_LEN 2048
#define B_SZ 2048

typedef float v2 __attribute__((ext_vector_type(2)));
#define FMA2(a, b, c) __builtin_elementwise_fma((a), (b), (c))

// Pure-VALU DPP move (quad_perm patterns; lane i receives sel_i).
template <int CTRL>
__device__ __forceinline__ float dppmov(float v) {
  int r = __builtin_amdgcn_update_dpp(0, __builtin_bit_cast(int, v), CTRL, 0xF,
                                      0xF, true);
  return __builtin_bit_cast(float, r);
}

// Decomposition (R10): ONE wave = 4 batches x 4 layers x 4 hidden units.
// lane = b*16 + l*4 + j. Each lane computes ALL 4 gates of hidden j for its
// (batch,layer): no gate-gather DPPs, cell update computed once (was 4x
// redundant). Quad = (b,l): h distribution = 3 fixed quad_perm rotations
// (hv[k] = h_{(j+k)&3}; wh pre-rotated accordingly). Layer skew = 2 ticks
// (layer l processes t = tau-2l). Handoff via an 8-region LDS ring:
// at tick tau (=8k+u), each lane WRITES h to region[u] and READS region
// [(u+7)&7] (written last tick, consumed next tick -> 1 full tick of DS
// latency slack). Region index is compile-time (unroll-8) => immediate
// offsets, zero per-tick address math. Region layout (floats):
// h[l][b][j] = l*16+b*4+j (64) | x-slot[b][0..3] = 64+b*4 ({x0,x1,0,0}).
// Layer-0 lanes read the x-slot instead of a previous layer's h.
// x staging + y output amortized: one burst per 8 ticks (u==7).
#define TICK(U)                                                                \
  {                                                                            \
    float4 nhin = *(const float4 *)(&Rf[(((U) + 7) & 7) * 80 + rd_off]);       \
    v2 h01, h23;                                                               \
    h01.x = hin.x;                                                             \
    h01.y = hin.y;                                                             \
    h23.x = hin.z;                                                             \
    h23.y = hin.w;                                                             \
    v2 A0 = FMA2(wi01[0], h01, bias2[0]);                                      \
    v2 A1 = FMA2(wi01[1], h01, bias2[1]);                                      \
    v2 A2 = FMA2(wi01[2], h01, bias2[2]);                                      \
    v2 A3 = FMA2(wi01[3], h01, bias2[3]);                                      \
    A0 = FMA2(wi23[0], h23, A0);                                               \
    A1 = FMA2(wi23[1], h23, A1);                                               \
    A2 = FMA2(wi23[2], h23, A2);                                               \
    A3 = FMA2(wi23[3], h23, A3);                                               \
    A0 = FMA2(wh01[0], hv01, A0);                                              \
    A1 = FMA2(wh01[1], hv01, A1);                                              \
    A2 = FMA2(wh01[2], hv01, A2);                                              \
    A3 = FMA2(wh01[3], hv01, A3);                                              \
    A0 = FMA2(wh23[0], hv23, A0);                                              \
    A1 = FMA2(wh23[1], hv23, A1);                                              \
    A2 = FMA2(wh23[2], hv23, A2);                                              \
    A3 = FMA2(wh23[3], hv23, A3);                                              \
    float a0 = A0.x + A0.y, a1 = A1.x + A1.y;                                  \
    float a2 = A2.x + A2.y, a3 = A3.x + A3.y;                                  \
    float e0 = __builtin_amdgcn_exp2f(a0); /* gates pre-scaled by kk_t */      \
    float e1 = __builtin_amdgcn_exp2f(a1);                                     \
    float e2 = __builtin_amdgcn_exp2f(a2);                                     \
    float e3 = __builtin_amdgcn_exp2f(a3);                                     \
    float r0 = __builtin_amdgcn_rcpf(1.0f + e0); /* sigmoid(i) */              \
    float r1 = __builtin_amdgcn_rcpf(1.0f + e1); /* sigmoid(f) */              \
    float r2 = __builtin_amdgcn_rcpf(1.0f + e2); /* (tanh(g)+1)/2 */           \
    float r3 = __builtin_amdgcn_rcpf(1.0f + e3); /* sigmoid(o) */              \
    float gi = KT * r0;                          /* KT fold: cKT = KT*c */     \
    float gg = fmaf(2.0f, r2, -1.0f);            /* tanh(g) */                 \
    cKT = fmaf(r1, cKT, gi * gg);                                              \
    float te = __builtin_amdgcn_exp2f(cKT);                                    \
    float tr = __builtin_amdgcn_rcpf(1.0f + te);                               \
    float go2 = r3 + r3;                                                       \
    float hh = fmaf(go2, tr, -r3); /* = o * tanh(c) */                         \
    Rf[(U) * 80 + wr_off] = hh;                                                \
    hv01.x = hh;                                                               \
    hv01.y = dppmov<0x39>(hh); /* h_{(j+1)&3} */                               \
    hv23.x = dppmov<0x4E>(hh); /* h_{(j+2)&3} */                               \
    hv23.y = dppmov<0x93>(hh); /* h_{(j+3)&3} */                               \
    hin = nhin;                                                                \
  }

// warm-up reset: layer l is live from tau = 2l
#define RESET(U)                                                               \
  if (2 * l > (U)) {                                                           \
    cKT = 0.0f;                                                                \
    hv01.x = 0.0f;                                                             \
    hv01.y = 0.0f;                                                             \
    hv23.x = 0.0f;                                                             \
    hv23.y = 0.0f;                                                             \
  }

#define PREFETCH()                                                             \
  {                                                                            \
    int ci = xi < ximax ? xi : ximax;                                          \
    gx = px[ci];                                                               \
    xi += 8 * B_SZ;                                                            \
  }

// u==7 burst: refill all 8 regions' x-slots (value for the NEXT epoch's
// read) + compute/store 8 ticks' worth of y from layer-3 h history.
#define REFILL_Y()                                                             \
  {                                                                            \
    *(float2 *)(&Rf[xw_off]) = gx;                                             \
    float4 h4 = *(const float4 *)(&Rf[r8 * 80 + 48 + bq * 4]);                 \
    float yv = fmaf(                                                           \
        wo3, h4.w,                                                             \
        fmaf(wo2, h4.z, fmaf(wo1, h4.y, fmaf(wo0, h4.x, bo))));                \
    if (lane < 32 && (unsigned)yi < (unsigned)(S_LEN * B_SZ)) outp[yi] = yv;   \
    yi += 8 * B_SZ;                                                            \
  }

__global__ void __launch_bounds__(64, 1)
    lstm_kernel(const float *__restrict__ x, const float *__restrict__ Wih0,
                const float *__restrict__ Whh0, const float *__restrict__ bih0,
                const float *__restrict__ bhh0, const float *__restrict__ Wihr,
                const float *__restrict__ Whhr, const float *__restrict__ bihr,
                const float *__restrict__ bhhr, const float *__restrict__ Wout,
                const float *__restrict__ bout, float *__restrict__ out) {
  // 8 regions x 80 floats + 64-float trash (for lanes 32-63's x-writes)
  __shared__ __align__(16) float Rf[704];

  const int lane = threadIdx.x & 63;
  const int b = lane >> 4;        // batch slot
  const int l = (lane >> 2) & 3;  // layer
  const int j = lane & 3;         // hidden unit
  const int bidx = blockIdx.x * 4 + b;
  const int r8 = lane & 7;          // burst: region / tick-slot index
  const int bq = (lane >> 3) & 3;   // burst: batch slot
  const int colq = blockIdx.x * 4 + bq;
  const int rd_off = (l == 0) ? (64 + b * 4) : ((l - 1) * 16 + b * 4);
  const int wr_off = l * 16 + b * 4 + j;
  const int xw_off =
      (lane < 32) ? (r8 * 80 + 64 + bq * 4) : (640 + (lane - 32) * 2);

// zero-init LDS (704 = 64*11): h slots, x pads, trash all finite
#pragma unroll
  for (int k = 0; k < 11; ++k) Rf[lane + 64 * k] = 0.0f;
  __builtin_amdgcn_wave_barrier();

  const float L2E = 1.4426950408889634f;
  const float KT = -2.8853900817779268f;  // -2*log2(e)
  const float kks[4] = {-L2E, -L2E, -2.0f * L2E, -L2E};

  // ---- per-lane weights: all 4 gates of hidden j, layer l; pk-paired,
  //      pre-scaled by kk_t; wh pre-rotated (wh[k] ~ Whh[row][(j+k)&3]) ----
  v2 wi01[4], wi23[4], wh01[4], wh23[4], bias2[4];
#pragma unroll
  for (int t = 0; t < 4; ++t) {
    const int row = t * 4 + j;
    const float kk = kks[t];
    float i0, i1, i2, i3, w0, w1, w2, w3, bs;
    if (l == 0) {
      i0 = Wih0[row * 2 + 0];
      i1 = Wih0[row * 2 + 1];
      i2 = 0.0f;
      i3 = 0.0f;
      w0 = Whh0[row * 4 + j];
      w1 = Whh0[row * 4 + ((j + 1) & 3)];
      w2 = Whh0[row * 4 + ((j + 2) & 3)];
      w3 = Whh0[row * 4 + ((j + 3) & 3)];
      bs = bih0[row] + bhh0[row];
    } else {
      const int m = l - 1;
      i0 = Wihr[m * 64 + row * 4 + 0];
      i1 = Wihr[m * 64 + row * 4 + 1];
      i2 = Wihr[m * 64 + row * 4 + 2];
      i3 = Wihr[m * 64 + row * 4 + 3];
      w0 = Whhr[m * 64 + row * 4 + j];
      w1 = Whhr[m * 64 + row * 4 + ((j + 1) & 3)];
      w2 = Whhr[m * 64 + row * 4 + ((j + 2) & 3)];
      w3 = Whhr[m * 64 + row * 4 + ((j + 3) & 3)];
      bs = bihr[m * 16 + row] + bhhr[m * 16 + row];
    }
    wi01[t].x = kk * i0;
    wi01[t].y = kk * i1;
    wi23[t].x = kk * i2;
    wi23[t].y = kk * i3;
    wh01[t].x = kk * w0;
    wh01[t].y = kk * w1;
    wh23[t].x = kk * w2;
    wh23[t].y = kk * w3;
    bias2[t].x = kk * bs;
    bias2[t].y = 0.0f;
  }
  const float wo0 = Wout[0], wo1 = Wout[1], wo2 = Wout[2], wo3 = Wout[3];
  const float bo = bout[0];

  // ---- state ----
  v2 hv01, hv23;
  hv01.x = 0.0f;
  hv01.y = 0.0f;
  hv23.x = 0.0f;
  hv23.y = 0.0f;
  float cKT = 0.0f;
  float4 hin;

  const float2 *__restrict__ px = (const float2 *)x;
  float *__restrict__ outp = out;

  // initial hin: layer-0 lanes get x(0), others 0
  {
    float2 xz = px[bidx];
    hin.x = (l == 0) ? xz.x : 0.0f;
    hin.y = (l == 0) ? xz.y : 0.0f;
    hin.z = 0.0f;
    hin.w = 0.0f;
  }

  // prime x-slots: region r holds x(t) consumed at tick r+1 (mod 8) + 1
  {
    int tp = 1 + ((r8 + 1) & 7);  // 1..8
    float2 xv = px[tp * B_SZ + colq];
    *(float2 *)(&Rf[xw_off]) = xv;
  }
  __builtin_amdgcn_wave_barrier();

  // burst indices
  int xi = (9 + ((r8 + 1) & 7)) * B_SZ + colq;  // float2 index of next refill
  const int ximax = (S_LEN - 1) * B_SZ + colq;  // clamp (drain never stored)
  int yi = (r8 - 6) * B_SZ + colq;              // y store index (t = 8k+v-6)
  float2 gx;

  // ---- epoch 0 (peeled: warm-up resets at u=0..5) ----
  PREFETCH();
  TICK(0); RESET(0);
  TICK(1); RESET(1);
  TICK(2); RESET(2);
  TICK(3); RESET(3);
  TICK(4); RESET(4);
  TICK(5); RESET(5);
  TICK(6);
  TICK(7);
  REFILL_Y();

  // ---- epochs 1..256: ticks tau = 8k..8k+7 ----
  for (int k = 1; k < 257; ++k) {
    PREFETCH();
    TICK(0);
    TICK(1);
    TICK(2);
    TICK(3);
    TICK(4);
    TICK(5);
    TICK(6);
    TICK(7);
    REFILL_Y();
  }
}

extern "C" void kernel_launch(void *const *d_in, const int *in_sizes, int n_in,
                              void *d_out, int out_size, void *d_ws,
                              size_t ws_size, hipStream_t stream) {
  (void)in_sizes;
  (void)n_in;
  (void)out_size;
  (void)d_ws;
  (void)ws_size;
  const float *x = (const float *)d_in[0];
  const float *Wih0 = (const float *)d_in[1];
  const float *Whh0 = (const float *)d_in[2];
  const float *bih0 = (const float *)d_in[3];
  const float *bhh0 = (const float *)d_in[4];
  const float *Wihr = (const float *)d_in[5];
  const float *Whhr = (const float *)d_in[6];
  const float *bihr = (const float *)d_in[7];
  const float *bhhr = (const float *)d_in[8];
  const float *Wout = (const float *)d_in[9];
  const float *bout = (const float *)d_in[10];
  lstm_kernel<<<dim3(B_SZ / 4), dim3(64), 0, stream>>>(
      x, Wih0, Whh0, bih0, bhh0, Wihr, Whhr, bihr, bhhr, Wout, bout,
      (float *)d_out);
}